// Round 5
// baseline (310.213 us; speedup 1.0000x reference)
//
#include <hip/hip_runtime.h>
#include <math.h>

// CapsuleLayer dynamic routing — round 5.
// B=64, N=4096, I=8, C=32, D=16, 3 routing iterations.
//
// vs round 4 (LDS-pipe-bound, 62 us/pass): W fragments now come straight
// from global (L2/L3) in a pre-transposed f16 layout (no LDS staging, no
// barrier in the K loop, 16 b of reuse per fragment), and the softmax
// reductions run on the VALU pipe via DPP (quad_perm / row_ror), leaving
// only 2 ds ops per (b,n).
//
// Layouts (all in ws):
//   Wh  f16 [n][k=0..7][l=0..63][8 i]   unit(n,k,l) = cj=l*8+k's 8 i's (32 MiB)
//   xh  f16 [n][b=0..63][8 i]           (4 MiB)
//   partial f16 [nb=128][bq=4][b=16][512 cj]  (8 MiB)
//   OcumG f16 [b=64][512 cj]            (64 KiB)
//
// fused_pass: grid 512 = 128 nb x 4 bq, 256 thr (4 waves). Wave w owns
// n = nb*32 + w*8 .. +7 and b = bq*16..+15. Lane l owns cj = l*8..+7
// (c = l>>1, j-octet = l&1). Per n: 8x global_load_dwordx4 W-frag
// (ping-pong prefetch), then 16 b-iters: 32 fdot2 hat, logit 4 fdot2,
// p += dpp_xor1; sum e over 32 c: dpp_xor2 + row_ror4 + row_ror8 +
// shfl_xor(16,32). acc f16x2 in regs. Epilogue: LDS cross-wave reduce
// (2 phases of 32KB), write f16 partial. reduce_squash: sum 128 nb,
// squash, Ocum update, out on pass 2.

typedef __fp16 h2 __attribute__((ext_vector_type(2)));

#define DPP_ADD(v, ctrl) ((v) + __int_as_float(__builtin_amdgcn_mov_dpp(__float_as_int(v), (ctrl), 0xf, 0xf, true)))
// quad_perm[1,0,3,2]=0xB1 (xor1), quad_perm[2,3,0,1]=0x4E (xor2),
// row_ror:4=0x124, row_ror:8=0x128

__device__ __forceinline__ float fdot2(h2 a, h2 b, float c) {
    return __builtin_amdgcn_fdot2(a, b, c, false);
}

// ---- pre-conversion kernels ------------------------------------------------

__global__ __launch_bounds__(256) void convertW(const float* __restrict__ W,
                                                ushort* __restrict__ Wh) {
    const int n = blockIdx.x, t = threadIdx.x;
    const int cj0 = 2 * t;                       // even
    const int c = cj0 >> 4, j0 = cj0 & 15;       // j0 even -> both cj in same c
    const float* src = W + (size_t)c * 524288 + (size_t)n * 128 + j0 * 8;
    float4 a = *reinterpret_cast<const float4*>(src);
    float4 b = *reinterpret_cast<const float4*>(src + 4);
    float4 cc = *reinterpret_cast<const float4*>(src + 8);
    float4 d = *reinterpret_cast<const float4*>(src + 12);
    __fp16 qa[8] = {(__fp16)a.x, (__fp16)a.y, (__fp16)a.z, (__fp16)a.w,
                    (__fp16)b.x, (__fp16)b.y, (__fp16)b.z, (__fp16)b.w};
    __fp16 qb[8] = {(__fp16)cc.x, (__fp16)cc.y, (__fp16)cc.z, (__fp16)cc.w,
                    (__fp16)d.x, (__fp16)d.y, (__fp16)d.z, (__fp16)d.w};
    uint4* dst = reinterpret_cast<uint4*>(Wh);
    const int l = t >> 2, k0 = cj0 & 7;          // cj0 = l*8 + k0
    dst[((size_t)n * 8 + k0) * 64 + l] = *reinterpret_cast<uint4*>(qa);
    dst[((size_t)n * 8 + k0 + 1) * 64 + l] = *reinterpret_cast<uint4*>(qb);
}

__global__ __launch_bounds__(256) void convertX(const float* __restrict__ x,
                                                ushort* __restrict__ xh) {
    const int gid = blockIdx.x * 256 + threadIdx.x;   // 0..262143
    const int b = gid >> 12, n = gid & 4095;
    const float* src = x + (size_t)b * 32768 + (size_t)n * 8;
    float4 a = *reinterpret_cast<const float4*>(src);
    float4 c = *reinterpret_cast<const float4*>(src + 4);
    __fp16 q[8] = {(__fp16)a.x, (__fp16)a.y, (__fp16)a.z, (__fp16)a.w,
                   (__fp16)c.x, (__fp16)c.y, (__fp16)c.z, (__fp16)c.w};
    reinterpret_cast<uint4*>(xh)[(size_t)n * 64 + b] = *reinterpret_cast<uint4*>(q);
}

// ---- main fused routing pass ----------------------------------------------

__device__ __forceinline__ void loadfrag(uint4 wv[8], const uint4* __restrict__ Whu,
                                         int n, int lane) {
    #pragma unroll
    for (int k = 0; k < 8; ++k) wv[k] = Whu[((size_t)n * 8 + k) * 64 + lane];
}

template <int UNI>
__global__ __launch_bounds__(256) void fused_pass(const ushort* __restrict__ Wh,
                                                  const ushort* __restrict__ xh,
                                                  const ushort* __restrict__ OcumG,
                                                  uint4* __restrict__ partialU,
                                                  int dummy) {
    const int nb = blockIdx.x >> 2, bq = blockIdx.x & 3;
    const int n0 = nb * 32, b0 = bq * 16;
    const int t = threadIdx.x, lane = t & 63, w = t >> 6;

    __shared__ __align__(16) char smem[32768];
    uint4* xlsu = reinterpret_cast<uint4*>(smem);        // 512 units: [nl 32][bl 16]
    uint4* ocmu = xlsu + 512;                            // 1024 units: [bl 16][l 64]

    const uint4* xhu = reinterpret_cast<const uint4*>(xh);
    for (int u = t; u < 512; u += 256) {
        int nl = u >> 4, bl = u & 15;
        xlsu[u] = xhu[(size_t)(n0 + nl) * 64 + b0 + bl];
    }
    if (!UNI) {
        const uint4* ocg = reinterpret_cast<const uint4*>(OcumG);
        for (int u = t; u < 1024; u += 256) {
            int bl = u >> 6, l = u & 63;
            ocmu[u] = ocg[(size_t)(b0 + bl) * 64 + l];
        }
    }
    __syncthreads();

    h2 acc[16][4];
    #pragma unroll
    for (int b = 0; b < 16; ++b)
        #pragma unroll
        for (int jp = 0; jp < 4; ++jp) acc[b][jp] = (h2)(__fp16)0.f;

    const uint4* Whu = reinterpret_cast<const uint4*>(Wh);
    const int nA = n0 + w * 8;

    uint4 wva[8], wvb[8];
    loadfrag(wva, Whu, nA, lane);

    #pragma unroll 1
    for (int s = 0; s < 8; s += 2) {
        loadfrag(wvb, Whu, nA + s + 1, lane);
        #pragma unroll 1
        for (int half = 0; half < 2; ++half) {
            const uint4* wv = half ? wvb : wva;
            const int nl = w * 8 + s + half;
            const h2* wh = reinterpret_cast<const h2*>(wv);
            const uint4* xrow = xlsu + nl * 16;
            #pragma unroll
            for (int b = 0; b < 16; ++b) {
                uint4 xv = xrow[b];                        // uniform addr: broadcast
                const h2* xp = reinterpret_cast<const h2*>(&xv);
                float h[8];
                #pragma unroll
                for (int k = 0; k < 8; ++k) {
                    float sacc = fdot2(wh[k * 4 + 0], xp[0], 0.f);
                    sacc = fdot2(wh[k * 4 + 1], xp[1], sacc);
                    sacc = fdot2(wh[k * 4 + 2], xp[2], sacc);
                    h[k] = fdot2(wh[k * 4 + 3], xp[3], sacc);
                }
                h2 hh[4];
                #pragma unroll
                for (int jp = 0; jp < 4; ++jp)
                    hh[jp] = __builtin_amdgcn_cvt_pkrtz(h[2 * jp], h[2 * jp + 1]);

                float ccf;
                if (UNI) {
                    ccf = 0.03125f;
                } else {
                    uint4 ov = ocmu[b * 64 + lane];
                    const h2* op = reinterpret_cast<const h2*>(&ov);
                    float p = fdot2(op[0], hh[0], 0.f);
                    p = fdot2(op[1], hh[1], p);
                    p = fdot2(op[2], hh[2], p);
                    p = fdot2(op[3], hh[3], p);
                    p = DPP_ADD(p, 0xB1);                  // + xor1: full logit per c
                    float e = __expf(p);                   // |p| small: no max-sub
                    float sm = e;
                    sm = DPP_ADD(sm, 0x4E);                // + xor2
                    sm = DPP_ADD(sm, 0x124);               // + row_ror:4
                    sm = DPP_ADD(sm, 0x128);               // + row_ror:8 -> row sum
                    sm += __shfl_xor(sm, 16, 64);
                    sm += __shfl_xor(sm, 32, 64);          // sum over all 32 c
                    ccf = e * __builtin_amdgcn_rcpf(sm);
                }
                h2 cs;
                cs.x = (__fp16)ccf;
                cs.y = cs.x;
                #pragma unroll
                for (int jp = 0; jp < 4; ++jp) acc[b][jp] = hh[jp] * cs + acc[b][jp];
            }
        }
        if (s + 2 < 8) loadfrag(wva, Whu, nA + s + 2, lane);
    }

    // ---- epilogue: cross-wave reduce in LDS (2 phases of 8 b), write partial
    uint4* ep = reinterpret_cast<uint4*>(smem);            // 2048 units = 32 KB
    const size_t pbase = (size_t)(nb * 4 + bq) * 1024;     // partial units per block
    #pragma unroll
    for (int ph = 0; ph < 2; ++ph) {
        __syncthreads();
        #pragma unroll
        for (int b = 0; b < 8; ++b)
            ep[(w * 8 + b) * 64 + lane] = *reinterpret_cast<uint4*>(&acc[ph * 8 + b][0]);
        __syncthreads();
        for (int o = t; o < 512; o += 256) {               // o = b*64 + l
            float sv[8] = {0.f, 0.f, 0.f, 0.f, 0.f, 0.f, 0.f, 0.f};
            #pragma unroll
            for (int ww = 0; ww < 4; ++ww) {
                uint4 v = ep[ww * 512 + o];
                const h2* vh = reinterpret_cast<const h2*>(&v);
                #pragma unroll
                for (int q = 0; q < 4; ++q) {
                    sv[2 * q] += (float)vh[q].x;
                    sv[2 * q + 1] += (float)vh[q].y;
                }
            }
            h2 pk[4];
            #pragma unroll
            for (int q = 0; q < 4; ++q)
                pk[q] = __builtin_amdgcn_cvt_pkrtz(sv[2 * q], sv[2 * q + 1]);
            partialU[pbase + (size_t)ph * 512 + o] = *reinterpret_cast<uint4*>(pk);
        }
    }
}

// ---- final reduce + squash + Ocum update ----------------------------------

__global__ __launch_bounds__(256) void reduce_squash(const unsigned* __restrict__ partial32,
                                                     ushort* __restrict__ OcumG,
                                                     float* __restrict__ out,
                                                     int passIdx) {
    const int tid = blockIdx.x * 256 + threadIdx.x;        // 0..16383
    const int b = tid >> 8, cjp = tid & 255;
    const int base = (b >> 4) * 4096 + (b & 15) * 256 + cjp;
    float sx = 0.f, sy = 0.f;
    for (int nb = 0; nb < 128; ++nb) {
        union { unsigned u; h2 h; } v;
        v.u = partial32[base + nb * 16384];
        sx += (float)v.h.x;
        sy += (float)v.h.y;
    }
    float s2 = sx * sx + sy * sy;                          // 16 j live in 8 threads
    s2 += __shfl_xor(s2, 1, 64);
    s2 += __shfl_xor(s2, 2, 64);
    s2 += __shfl_xor(s2, 4, 64);
    float scale = (s2 / (1.f + s2)) / sqrtf(s2 + 1e-7f);
    float o0 = scale * sx, o1 = scale * sy;

    unsigned* ocp = reinterpret_cast<unsigned*>(OcumG) + b * 256 + cjp;
    float a0 = o0, a1 = o1;
    if (passIdx) {
        union { unsigned u; h2 h; } old;
        old.u = *ocp;
        a0 += (float)old.h.x;
        a1 += (float)old.h.y;
    }
    union { h2 h; unsigned u; } nw;
    nw.h = __builtin_amdgcn_cvt_pkrtz(a0, a1);
    *ocp = nw.u;

    if (passIdx == 2) {
        out[b * 512 + cjp * 2] = o0;
        out[b * 512 + cjp * 2 + 1] = o1;
    }
}

// ---- host ------------------------------------------------------------------

extern "C" void kernel_launch(void* const* d_in, const int* in_sizes, int n_in,
                              void* d_out, int out_size, void* d_ws, size_t ws_size,
                              hipStream_t stream) {
    const float* x = (const float*)d_in[0];
    const float* W = (const float*)d_in[1];
    float* out = (float*)d_out;

    char* ws = (char*)d_ws;
    ushort* Wh = (ushort*)ws;                                   // 32 MiB
    ushort* xh = (ushort*)(ws + (size_t)32 * 1024 * 1024);      // 4 MiB
    uint4* partialU = (uint4*)(ws + (size_t)36 * 1024 * 1024);  // 8 MiB
    ushort* OcumG = (ushort*)(ws + (size_t)44 * 1024 * 1024);   // 64 KiB

    convertW<<<4096, 256, 0, stream>>>(W, Wh);
    convertX<<<1024, 256, 0, stream>>>(x, xh);

    for (int pass = 0; pass < 3; ++pass) {
        if (pass == 0)
            fused_pass<1><<<512, 256, 0, stream>>>(Wh, xh, OcumG, partialU, 0);
        else
            fused_pass<0><<<512, 256, 0, stream>>>(Wh, xh, OcumG, partialU, 0);
        reduce_squash<<<64, 256, 0, stream>>>((const unsigned*)partialU, OcumG, out, pass);
    }
}